// Round 1
// baseline (915.311 us; speedup 1.0000x reference)
//
#include <hip/hip_runtime.h>
#include <hip/hip_bf16.h>

#define BB 16
#define XY 64
#define CC 256
#define PD 66   // padded spatial (64 + 1 halo each side)
#define KC 32   // ci chunk staged in LDS

// ---------------- Kernel 1: conv1(1->C,3x3) + BN1 + ReLU -> padded NHWC act ----
// grid: BB*PD blocks (one padded row each), 256 threads (= channels)
__global__ __launch_bounds__(256) void k_conv1(
    const float* __restrict__ in,      // (B,64,64)
    const float* __restrict__ w1,      // (C,1,3,3)
    const float* __restrict__ g, const float* __restrict__ bbias,
    const float* __restrict__ m, const float* __restrict__ v,
    float* __restrict__ act)           // (B,66,66,C) zero-padded
{
  int blk = blockIdx.x;
  int b = blk / PD, hp = blk % PD;
  int c = threadIdx.x;
  float* actrow = act + (size_t)(b * PD + hp) * PD * CC;
  if (hp == 0 || hp == PD - 1) {
    for (int wp = 0; wp < PD; ++wp) actrow[wp * CC + c] = 0.f;
    return;
  }
  __shared__ float inrow[3][PD];
  int h = hp - 1;
  for (int t = threadIdx.x; t < 3 * PD; t += 256) {
    int r = t / PD, x = t % PD;
    int hr = h - 1 + r, wr = x - 1;
    inrow[r][x] = (hr >= 0 && hr < XY && wr >= 0 && wr < XY)
                      ? in[(b * XY + hr) * XY + wr] : 0.f;
  }
  __syncthreads();
  float w[9];
#pragma unroll
  for (int t = 0; t < 9; ++t) w[t] = w1[c * 9 + t];
  float s  = g[c] * rsqrtf(v[c] + 1e-5f);
  float tt = bbias[c] - m[c] * s;
  actrow[c] = 0.f;                    // wp = 0 pad
  actrow[(PD - 1) * CC + c] = 0.f;    // wp = 65 pad
  for (int wp = 1; wp <= XY; ++wp) {
    float o = 0.f;
#pragma unroll
    for (int dy = 0; dy < 3; ++dy)
#pragma unroll
      for (int dx = 0; dx < 3; ++dx)
        o = fmaf(inrow[dy][wp - 1 + dx], w[dy * 3 + dx], o);
    actrow[wp * CC + c] = fmaxf(fmaf(o, s, tt), 0.f);
  }
}

// ---------------- Kernel 2: transpose conv2_w -> Wt[tap][ci][co], fold BN2 scale
__global__ __launch_bounds__(256) void k_wt(
    const float* __restrict__ w2,      // (co, ci, 3, 3)
    const float* __restrict__ g, const float* __restrict__ v,
    float* __restrict__ Wt)            // (9, ci, co)
{
  int e = blockIdx.x * 256 + threadIdx.x;  // < 9*256*256
  int co = e % CC;
  int rest = e / CC;
  int ci = rest % CC;
  int tap = rest / CC;
  float s = g[co] * rsqrtf(v[co] + 1e-5f);
  Wt[e] = w2[(co * CC + ci) * 9 + tap] * s;
}

// ---------------- Kernel 3: conv2 + BN2 + ReLU + residual-add + ReLU -> out ----
// grid: BB*XY blocks (one output image-row each), 256 threads
// thread (tr,tc): tr=tid>>4 owns w = tr*4+{0..3}; tc=tid&15 owns
// co = tc*4 + (j&3) + (j>>2)*64  (this mapping makes Ws b128 reads 2-way on banks)
__global__ __launch_bounds__(256, 2) void k_conv2(
    const float* __restrict__ act,     // (B,66,66,C)
    const float* __restrict__ Wt,      // (9,ci,co) pre-scaled by s2
    const float* __restrict__ in,      // (B,64,64)
    const float* __restrict__ g2, const float* __restrict__ b2,
    const float* __restrict__ m2, const float* __restrict__ v2,
    float* __restrict__ out)           // (B,4096,C)
{
  __shared__ float As[3][PD][36];      // 36-pad: tr-stride 144 %32banks = 16 -> 2-way (free)
  __shared__ float Ws[KC][CC];         // 32 KiB

  int blk = blockIdx.x;
  int b = blk / XY, h = blk % XY;
  int tid = threadIdx.x;
  int tc = tid & 15, tr = tid >> 4;

  float acc[4][16];
#pragma unroll
  for (int i = 0; i < 4; ++i)
#pragma unroll
    for (int j = 0; j < 16; ++j) acc[i][j] = 0.f;

  const float* actbase = act + (size_t)(b * PD + h) * PD * CC;

  for (int ci0 = 0; ci0 < CC; ci0 += KC) {
    __syncthreads();  // previous chunk's compute done before As overwrite
    // stage A: rows h..h+2 (padded), 66 cols, KC channels
    for (int idx = tid; idx < 3 * PD * (KC / 4); idx += 256) {
      int jg = idx & 7;        // KC/4 = 8 float4 groups
      int p  = idx >> 3;       // r*66 + wp
      int r = p / PD, wp = p % PD;
      float4 val = *(const float4*)(actbase + ((size_t)(r * PD + wp)) * CC + ci0 + jg * 4);
      *(float4*)&As[r][wp][jg * 4] = val;
    }
    for (int tap = 0; tap < 9; ++tap) {
      int dy = tap / 3, dx = tap % 3;
      __syncthreads();  // prev tap compute done (Ws), A stage visible
      const float4* wsrc = (const float4*)(Wt + ((size_t)tap * CC + ci0) * CC);
#pragma unroll
      for (int i = 0; i < 8; ++i)
        ((float4*)Ws)[i * 256 + tid] = wsrc[i * 256 + tid];
      __syncthreads();

      const float* Ap = &As[dy][tr * 4 + dx][0];
#pragma unroll 2
      for (int ci = 0; ci < KC; ++ci) {
        float av[4];
        av[0] = Ap[ci];
        av[1] = Ap[36 + ci];
        av[2] = Ap[72 + ci];
        av[3] = Ap[108 + ci];
        const float* wrow = &Ws[ci][tc * 4];
        float4 wq[4];
        wq[0] = *(const float4*)(wrow);
        wq[1] = *(const float4*)(wrow + 64);
        wq[2] = *(const float4*)(wrow + 128);
        wq[3] = *(const float4*)(wrow + 192);
        const float* wf = (const float*)wq;
#pragma unroll
        for (int i = 0; i < 4; ++i)
#pragma unroll
          for (int j = 0; j < 16; ++j)
            acc[i][j] = fmaf(av[i], wf[j], acc[i][j]);
      }
    }
  }

  // epilogue: +t2, ReLU, +input (broadcast over co), ReLU, NHWC store
  float t2v[16];
#pragma unroll
  for (int j = 0; j < 16; ++j) {
    int co = tc * 4 + (j & 3) + (j >> 2) * 64;
    float s2 = g2[co] * rsqrtf(v2[co] + 1e-5f);
    t2v[j] = b2[co] - m2[co] * s2;
  }
  const float* inb = in + (b * XY + h) * XY;
  float* ob = out + (size_t)(b * XY + h) * XY * CC;
#pragma unroll
  for (int i = 0; i < 4; ++i) {
    int w_ = tr * 4 + i;
    float iv = inb[w_];
    float res[16];
#pragma unroll
    for (int j = 0; j < 16; ++j) {
      float a2v = fmaxf(acc[i][j] + t2v[j], 0.f);
      res[j] = fmaxf(iv + a2v, 0.f);
    }
    float* op = ob + (size_t)w_ * CC + tc * 4;
#pragma unroll
    for (int k = 0; k < 4; ++k)
      *(float4*)(op + k * 64) = make_float4(res[k*4+0], res[k*4+1], res[k*4+2], res[k*4+3]);
  }
}

extern "C" void kernel_launch(void* const* d_in, const int* in_sizes, int n_in,
                              void* d_out, int out_size, void* d_ws, size_t ws_size,
                              hipStream_t stream) {
  const float* in_   = (const float*)d_in[0];   // (16,64,64)
  const float* w1    = (const float*)d_in[3];   // (256,1,3,3)
  const float* w2    = (const float*)d_in[4];   // (256,256,3,3)
  const float* bn1_g = (const float*)d_in[5];
  const float* bn1_b = (const float*)d_in[6];
  const float* bn1_m = (const float*)d_in[7];
  const float* bn1_v = (const float*)d_in[8];
  const float* bn2_g = (const float*)d_in[9];
  const float* bn2_b = (const float*)d_in[10];
  const float* bn2_m = (const float*)d_in[11];
  const float* bn2_v = (const float*)d_in[12];
  float* out = (float*)d_out;

  // workspace layout (fp32): act (B,66,66,C) then Wt (9,C,C)
  float* act = (float*)d_ws;
  float* Wt  = act + (size_t)BB * PD * PD * CC;   // 17,842,176 floats

  k_conv1<<<BB * PD, 256, 0, stream>>>(in_, w1, bn1_g, bn1_b, bn1_m, bn1_v, act);
  k_wt<<<(9 * CC * CC) / 256, 256, 0, stream>>>(w2, bn2_g, bn2_v, Wt);
  k_conv2<<<BB * XY, 256, 0, stream>>>(act, Wt, in_, bn2_g, bn2_b, bn2_m, bn2_v, out);
}

// Round 2
// 102.837 us; speedup vs baseline: 8.9006x; 8.9006x over previous
//
#include <hip/hip_runtime.h>
#include <hip/hip_bf16.h>

#define BB 16
#define XY 64
#define CC 256
#define PD 66   // padded spatial (64 + 1 halo each side)

typedef __attribute__((ext_vector_type(8))) short short8;
typedef __attribute__((ext_vector_type(4))) float f32x4;
typedef __hip_bfloat16 bf16;

__device__ __forceinline__ void glds16(const void* g, void* l) {
  __builtin_amdgcn_global_load_lds(
      (const __attribute__((address_space(1))) void*)g,
      (__attribute__((address_space(3))) void*)l, 16, 0, 0);
}

// ---------------- Kernel 1: conv1(1->C,3x3) + BN1 + ReLU -> padded NHWC bf16 act
// grid: BB*PD blocks (one padded row each), 256 threads (= channels)
__global__ __launch_bounds__(256) void k_conv1(
    const float* __restrict__ in,      // (B,64,64)
    const float* __restrict__ w1,      // (C,1,3,3)
    const float* __restrict__ g, const float* __restrict__ bbias,
    const float* __restrict__ m, const float* __restrict__ v,
    bf16* __restrict__ act)            // (B,66,66,C) zero-padded bf16
{
  int blk = blockIdx.x;
  int b = blk / PD, hp = blk % PD;
  int c = threadIdx.x;
  bf16* actrow = act + (size_t)(b * PD + hp) * PD * CC;
  if (hp == 0 || hp == PD - 1) {
    for (int wp = 0; wp < PD; ++wp) actrow[wp * CC + c] = __float2bfloat16(0.f);
    return;
  }
  __shared__ float inrow[3][PD];
  int h = hp - 1;
  for (int t = threadIdx.x; t < 3 * PD; t += 256) {
    int r = t / PD, x = t % PD;
    int hr = h - 1 + r, wr = x - 1;
    inrow[r][x] = (hr >= 0 && hr < XY && wr >= 0 && wr < XY)
                      ? in[(b * XY + hr) * XY + wr] : 0.f;
  }
  __syncthreads();
  float w[9];
#pragma unroll
  for (int t = 0; t < 9; ++t) w[t] = w1[c * 9 + t];
  float s  = g[c] * rsqrtf(v[c] + 1e-5f);
  float tt = bbias[c] - m[c] * s;
  actrow[c] = __float2bfloat16(0.f);
  actrow[(PD - 1) * CC + c] = __float2bfloat16(0.f);
  for (int wp = 1; wp <= XY; ++wp) {
    float o = 0.f;
#pragma unroll
    for (int dy = 0; dy < 3; ++dy)
#pragma unroll
      for (int dx = 0; dx < 3; ++dx)
        o = fmaf(inrow[dy][wp - 1 + dx], w[dy * 3 + dx], o);
    actrow[wp * CC + c] = __float2bfloat16(fmaxf(fmaf(o, s, tt), 0.f));
  }
}

// ---------------- Kernel 2: w2 -> Wb[tap][c][qq][co][8] bf16, BN2 scale folded
// ci = c*32 + qq*8 + j ; flat e = (((tap*8+c)*4+qq)*256+co)*8 + j
__global__ __launch_bounds__(256) void k_wb(
    const float* __restrict__ w2,      // (co, ci, 3, 3)
    const float* __restrict__ g, const float* __restrict__ v,
    bf16* __restrict__ Wb)
{
  int e = blockIdx.x * 256 + threadIdx.x;   // < 589824
  int j   = e & 7;
  int co  = (e >> 3) & 255;
  int qq  = (e >> 11) & 3;
  int c   = (e >> 13) & 7;
  int tap = e >> 16;
  int ci = c * 32 + qq * 8 + j;
  float s = g[co] * rsqrtf(v[co] + 1e-5f);
  Wb[e] = __float2bfloat16(w2[((size_t)co * CC + ci) * 9 + tap] * s);
}

// ---------------- Kernel 3: conv2 via MFMA + BN2 + ReLU + residual + ReLU ------
// grid: BB*XY blocks (one output row: M=64, N=256), 256 threads = 4 waves.
// wave wv owns co range [wv*64, wv*64+64); per wave 4 m-tiles x 4 n-tiles of 16x16.
__global__ __launch_bounds__(256, 3) void k_conv2(
    const bf16* __restrict__ act,      // (B,66,66,256) padded NHWC bf16
    const bf16* __restrict__ Wb,       // (9,8,4,256,8) bf16 pre-scaled
    const float* __restrict__ in,      // (B,64,64) residual
    const float* __restrict__ g2, const float* __restrict__ b2,
    const float* __restrict__ m2, const float* __restrict__ v2,
    float* __restrict__ out)           // (B,4096,256)
{
  __shared__ alignas(16) bf16 As[3 * 4 * PD * 8];  // [(r*4+qq)*66+wp][8]  12.4 KB
  __shared__ alignas(16) bf16 Ws[4 * CC * 8];      // [(q*256+co)][8]     16 KB
  __shared__ float inrow[XY];

  int blk = blockIdx.x;
  int b = blk >> 6, h = blk & 63;
  int tid = threadIdx.x;
  int lane = tid & 63, wv = tid >> 6;
  int m = lane & 15, q = lane >> 4;

  f32x4 acc[4][4];
#pragma unroll
  for (int i = 0; i < 4; ++i)
#pragma unroll
    for (int j = 0; j < 4; ++j) acc[i][j] = f32x4{0.f, 0.f, 0.f, 0.f};

  if (tid < XY) inrow[tid] = in[(b * XY + h) * XY + tid];

  const bf16* actbase = act + (size_t)(b * PD + h) * PD * CC;

  for (int c = 0; c < 8; ++c) {
    for (int tap = 0; tap < 9; ++tap) {
      // stage W(tap,c): 16 KB contiguous via global_load_lds (wave wv: 4 x 1KB)
      const bf16* wsrc = Wb + (size_t)(tap * 8 + c) * 8192;
#pragma unroll
      for (int i = 0; i < 4; ++i) {
        int seg = wv * 4 + i;
        glds16((const char*)wsrc + seg * 1024 + lane * 16,
               (char*)Ws + seg * 1024);
      }
      if (tap == 0) {
        // stage A(c): 3 rows x 66 wp x 4 qq = 792 chunks of 16B, reg->LDS
        for (int idx = tid; idx < 792; idx += 256) {
          int qq = idx & 3, p = idx >> 2;
          int r = p / PD, wp = p % PD;
          short8 val = *(const short8*)(actbase + (size_t)(r * PD + wp) * CC + c * 32 + qq * 8);
          *(short8*)&As[((r * 4 + qq) * PD + wp) * 8] = val;
        }
      }
      __syncthreads();   // drains vmcnt (glds) + lgkm (ds_write)

      int dy = tap / 3, dx = tap % 3;
      short8 af[4], bfr[4];
#pragma unroll
      for (int mt = 0; mt < 4; ++mt)
        af[mt] = *(const short8*)&As[((dy * 4 + q) * PD + mt * 16 + m + dx) * 8];
#pragma unroll
      for (int nt = 0; nt < 4; ++nt)
        bfr[nt] = *(const short8*)&Ws[(q * CC + wv * 64 + nt * 16 + m) * 8];
#pragma unroll
      for (int mt = 0; mt < 4; ++mt)
#pragma unroll
        for (int nt = 0; nt < 4; ++nt)
          acc[mt][nt] = __builtin_amdgcn_mfma_f32_16x16x32_bf16(
              af[mt], bfr[nt], acc[mt][nt], 0, 0, 0);
      __syncthreads();   // protect As/Ws before next stage
    }
  }

  // epilogue: +t2, ReLU, +input (broadcast over co), ReLU
  // C/D layout: col = lane&15 (co), row = q*4 + reg (wp)  [m89-verified]
  float t2[4];
#pragma unroll
  for (int nt = 0; nt < 4; ++nt) {
    int co = wv * 64 + nt * 16 + m;
    float s2 = g2[co] * rsqrtf(v2[co] + 1e-5f);
    t2[nt] = b2[co] - m2[co] * s2;
  }
  float* ob = out + (size_t)(b * XY + h) * XY * CC;
#pragma unroll
  for (int mt = 0; mt < 4; ++mt)
#pragma unroll
    for (int r = 0; r < 4; ++r) {
      int wp = mt * 16 + q * 4 + r;
      float iv = inrow[wp];
#pragma unroll
      for (int nt = 0; nt < 4; ++nt) {
        int co = wv * 64 + nt * 16 + m;
        float val = fmaxf(acc[mt][nt][r] + t2[nt], 0.f);
        ob[(size_t)wp * CC + co] = fmaxf(iv + val, 0.f);
      }
    }
}

extern "C" void kernel_launch(void* const* d_in, const int* in_sizes, int n_in,
                              void* d_out, int out_size, void* d_ws, size_t ws_size,
                              hipStream_t stream) {
  const float* in_   = (const float*)d_in[0];   // (16,64,64)
  const float* w1    = (const float*)d_in[3];   // (256,1,3,3)
  const float* w2    = (const float*)d_in[4];   // (256,256,3,3)
  const float* bn1_g = (const float*)d_in[5];
  const float* bn1_b = (const float*)d_in[6];
  const float* bn1_m = (const float*)d_in[7];
  const float* bn1_v = (const float*)d_in[8];
  const float* bn2_g = (const float*)d_in[9];
  const float* bn2_b = (const float*)d_in[10];
  const float* bn2_m = (const float*)d_in[11];
  const float* bn2_v = (const float*)d_in[12];
  float* out = (float*)d_out;

  // workspace: act bf16 (B,66,66,256) = 35.7 MB, then Wb bf16 (9,8,4,256,8) = 1.18 MB
  bf16* act = (bf16*)d_ws;
  bf16* Wb  = act + (size_t)BB * PD * PD * CC;

  k_conv1<<<BB * PD, 256, 0, stream>>>(in_, w1, bn1_g, bn1_b, bn1_m, bn1_v, act);
  k_wb<<<(9 * CC * CC) / 256, 256, 0, stream>>>(w2, bn2_g, bn2_v, Wb);
  k_conv2<<<BB * XY, 256, 0, stream>>>(act, Wb, in_, bn2_g, bn2_b, bn2_m, bn2_v, out);
}

// Round 3
// 98.876 us; speedup vs baseline: 9.2572x; 1.0401x over previous
//
#include <hip/hip_runtime.h>
#include <hip/hip_bf16.h>

#define BB 16
#define XY 64
#define CC 256
#define PD 66   // padded spatial (64 + 1 halo each side)
#define AST 67  // As row-group stride in 16B chunks (67: q-groups land on distinct banks)

typedef __attribute__((ext_vector_type(8))) short short8;
typedef __attribute__((ext_vector_type(4))) float f32x4;
typedef __hip_bfloat16 bf16;
typedef __hip_bfloat162 bf16x2;

__device__ __forceinline__ void glds16(const void* g, void* l) {
  __builtin_amdgcn_global_load_lds(
      (const __attribute__((address_space(1))) void*)g,
      (__attribute__((address_space(3))) void*)l, 16, 0, 0);
}

// ---------------- Kernel 1: conv1(1->C,3x3) + BN1 + ReLU -> padded NHWC bf16 act
// 256 threads: cp=tid&127 handles channel pair (2cp, 2cp+1); half=tid>>7 covers
// wp 1..32 / 33..64. Stores bf16x2 (4B/lane, fully coalesced).
__global__ __launch_bounds__(256) void k_conv1(
    const float* __restrict__ in,      // (B,64,64)
    const float* __restrict__ w1,      // (C,1,3,3)
    const float* __restrict__ g, const float* __restrict__ bbias,
    const float* __restrict__ m, const float* __restrict__ v,
    bf16* __restrict__ act)            // (B,66,66,C) zero-padded bf16
{
  int blk = blockIdx.x;
  int b = blk / PD, hp = blk % PD;
  int tid = threadIdx.x;
  bf16x2* actrow = (bf16x2*)(act + (size_t)(b * PD + hp) * PD * CC);
  bf16x2 z; z.x = __float2bfloat16(0.f); z.y = z.x;
  if (hp == 0 || hp == PD - 1) {
    for (int i = tid; i < PD * 128; i += 256) actrow[i] = z;
    return;
  }
  __shared__ float inrow[3][PD];
  int h = hp - 1;
  for (int t = tid; t < 3 * PD; t += 256) {
    int r = t / PD, x = t % PD;
    int hr = h - 1 + r, wr = x - 1;
    inrow[r][x] = (hr >= 0 && hr < XY && wr >= 0 && wr < XY)
                      ? in[(b * XY + hr) * XY + wr] : 0.f;
  }
  __syncthreads();
  int cp = tid & 127, half = tid >> 7;
  int c0 = cp * 2;
  float wa[9], wb_[9];
#pragma unroll
  for (int t = 0; t < 9; ++t) { wa[t] = w1[c0 * 9 + t]; wb_[t] = w1[(c0 + 1) * 9 + t]; }
  float s0 = g[c0] * rsqrtf(v[c0] + 1e-5f),     t0 = bbias[c0] - m[c0] * s0;
  float s1 = g[c0+1] * rsqrtf(v[c0+1] + 1e-5f), t1 = bbias[c0+1] - m[c0+1] * s1;
  actrow[(half ? (PD - 1) : 0) * 128 + cp] = z;   // col padding
  for (int i = 0; i < 32; ++i) {
    int wp = half * 32 + 1 + i;
    float o0 = 0.f, o1 = 0.f;
#pragma unroll
    for (int dy = 0; dy < 3; ++dy)
#pragma unroll
      for (int dx = 0; dx < 3; ++dx) {
        float iv = inrow[dy][wp - 1 + dx];
        o0 = fmaf(iv, wa[dy * 3 + dx], o0);
        o1 = fmaf(iv, wb_[dy * 3 + dx], o1);
      }
    bf16x2 rr;
    rr.x = __float2bfloat16(fmaxf(fmaf(o0, s0, t0), 0.f));
    rr.y = __float2bfloat16(fmaxf(fmaf(o1, s1, t1), 0.f));
    actrow[wp * 128 + cp] = rr;
  }
}

// ---------------- Kernel 2: w2 -> Wb bf16, BN2 scale folded, XOR-swizzled layout
// Physical chunk P (16B) within each (tap,cc) 16KB block holds logical chunk
// L = P ^ ((P>>8)<<1)   (involution; reader reads P = L ^ (q<<1) -> bank spread)
// logical L = qq*256 + co ; data j=0..7 -> ci = cc*32 + qq*8 + j
__global__ __launch_bounds__(256) void k_wb(
    const float* __restrict__ w2,      // (co, ci, 3, 3)
    const float* __restrict__ g, const float* __restrict__ v,
    bf16* __restrict__ Wb)
{
  int e = blockIdx.x * 256 + threadIdx.x;   // < 9*8*1024*8 = 589824
  int j   = e & 7;
  int P   = (e >> 3) & 1023;
  int cc  = (e >> 13) & 7;
  int tap = e >> 16;
  int L = P ^ (((P >> 8) & 3) << 1);
  int qq = L >> 8, co = L & 255;
  int ci = cc * 32 + qq * 8 + j;
  float s = g[co] * rsqrtf(v[co] + 1e-5f);
  Wb[e] = __float2bfloat16(w2[((size_t)co * CC + ci) * 9 + tap] * s);
}

// ---------------- Kernel 3: conv2 via MFMA, counted-vmcnt W pipeline ----------
// grid 512: block = 2 output rows (M=128) x N=256. 4 waves; wave wv owns co
// [wv*64, wv*64+64). 72 K-steps (c-chunk x tap); W double-buffered in LDS,
// next stage's 4 glds16 stay in flight across both barriers (vmcnt(4)).
__global__ __launch_bounds__(256, 2) void k_conv2(
    const bf16* __restrict__ act,      // (B,66,66,256) padded NHWC bf16
    const bf16* __restrict__ Wb,       // swizzled (9,8,1024,8) bf16
    const float* __restrict__ in,      // (B,64,64) residual
    const float* __restrict__ g2, const float* __restrict__ b2,
    const float* __restrict__ m2, const float* __restrict__ v2,
    float* __restrict__ out)           // (B,4096,256)
{
  __shared__ alignas(16) bf16 As[16 * AST * 8];   // 17152 B  [(r*4+qq)*67+wp][8]
  __shared__ alignas(16) bf16 Ws[2][1024 * 8];    // 32768 B  double-buffered
  __shared__ float inrow[128];

  // XCD-aware swizzle (512 % 8 == 0 -> simple form valid)
  int gg = blockIdx.x;
  int blk = (gg & 7) * 64 + (gg >> 3);
  int b = blk >> 5, h0 = (blk & 31) * 2;

  int tid = threadIdx.x;
  int lane = tid & 63, wv = tid >> 6;
  int m = lane & 15, q = lane >> 4;

  f32x4 acc[8][4];
#pragma unroll
  for (int i = 0; i < 8; ++i)
#pragma unroll
    for (int j = 0; j < 4; ++j) acc[i][j] = f32x4{0.f, 0.f, 0.f, 0.f};

  if (tid < 128) inrow[tid] = in[(b * XY + h0 + (tid >> 6)) * XY + (tid & 63)];
  __syncthreads();   // drains inrow (vmcnt+lgkm) before counted region begins

  const bf16* actbase = act + ((size_t)(b * PD) + h0) * PD * CC;

  // prologue: stage W(kt=0) -> Ws[0]
#pragma unroll
  for (int i = 0; i < 4; ++i) {
    int seg = wv * 4 + i;
    glds16((const char*)Wb + seg * 1024 + lane * 16, (char*)&Ws[0][0] + seg * 1024);
  }

  int kt = 0;
  for (int c = 0; c < 8; ++c) {
    for (int tap = 0; tap < 9; ++tap, ++kt) {
      int cur = kt & 1;
      __builtin_amdgcn_s_barrier();   // B1: all reads of Ws[cur^1] / As(prev c) done
      short8 areg[4], aregR;
      if (tap == 0) {                  // issue A loads FIRST (oldest in vmcnt FIFO)
#pragma unroll
        for (int i = 0; i < 4; ++i) {
          int idx = tid + i * 256;
          int qq = idx & 3, p = idx >> 2;
          int r = p / PD, wp = p % PD;
          areg[i] = *(const short8*)(actbase + ((size_t)(r * PD + wp)) * CC + c * 32 + qq * 8);
        }
        if (tid < 32) {
          int idx = 1024 + tid;
          int qq = idx & 3, p = idx >> 2;
          int r = p / PD, wp = p % PD;
          aregR = *(const short8*)(actbase + ((size_t)(r * PD + wp)) * CC + c * 32 + qq * 8);
        }
        __builtin_amdgcn_sched_barrier(0);  // keep A-loads above the glds issues
      }
      if (kt + 1 < 72) {
        int tap1 = (tap == 8) ? 0 : tap + 1;
        int c1   = (tap == 8) ? c + 1 : c;
        const bf16* wsrc = Wb + (size_t)(tap1 * 8 + c1) * 8192;
#pragma unroll
        for (int i = 0; i < 4; ++i) {
          int seg = wv * 4 + i;
          glds16((const char*)wsrc + seg * 1024 + lane * 16,
                 (char*)&Ws[cur ^ 1][0] + seg * 1024);
        }
        // drain stage(kt) + A-loads; leave stage(kt+1)'s 4 glds in flight
        asm volatile("s_waitcnt vmcnt(4)" ::: "memory");
      } else {
        asm volatile("s_waitcnt vmcnt(0)" ::: "memory");
      }
      if (tap == 0) {
#pragma unroll
        for (int i = 0; i < 4; ++i) {
          int idx = tid + i * 256;
          int qq = idx & 3, p = idx >> 2;
          int r = p / PD, wp = p % PD;
          *(short8*)&As[((r * 4 + qq) * AST + wp) * 8] = areg[i];
        }
        if (tid < 32) {
          int idx = 1024 + tid;
          int qq = idx & 3, p = idx >> 2;
          int r = p / PD, wp = p % PD;
          *(short8*)&As[((r * 4 + qq) * AST + wp) * 8] = aregR;
        }
        asm volatile("s_waitcnt lgkmcnt(0)" ::: "memory");
      }
      __builtin_amdgcn_s_barrier();   // B2: Ws[cur] + As(c) visible to all waves
      __builtin_amdgcn_sched_barrier(0);

      int dy = tap / 3, dx = tap % 3;
      short8 af[8], bfr[4];
#pragma unroll
      for (int mt = 0; mt < 8; ++mt) {
        int rg = (mt >> 2) + dy;              // padded row-group
        int wp = (mt & 3) * 16 + m + dx;      // padded col chunk
        af[mt] = *(const short8*)&As[((rg * 4 + q) * AST + wp) * 8];
      }
#pragma unroll
      for (int nt = 0; nt < 4; ++nt) {
        int Lc = (q << 8) + (wv << 6) + nt * 16 + m;
        bfr[nt] = *(const short8*)&Ws[cur][(Lc ^ (q << 1)) * 8];
      }
      __builtin_amdgcn_s_setprio(1);
#pragma unroll
      for (int mt = 0; mt < 8; ++mt)
#pragma unroll
        for (int nt = 0; nt < 4; ++nt)
          acc[mt][nt] = __builtin_amdgcn_mfma_f32_16x16x32_bf16(
              af[mt], bfr[nt], acc[mt][nt], 0, 0, 0);
      __builtin_amdgcn_s_setprio(0);
    }
  }

  // epilogue: +t2, ReLU, +input, ReLU.  C/D: col=lane&15, row=q*4+reg
  float t2[4];
#pragma unroll
  for (int nt = 0; nt < 4; ++nt) {
    int co = (wv << 6) + nt * 16 + m;
    float s2 = g2[co] * rsqrtf(v2[co] + 1e-5f);
    t2[nt] = b2[co] - m2[co] * s2;
  }
#pragma unroll
  for (int mt = 0; mt < 8; ++mt) {
    int r_out = mt >> 2;
    float* ob = out + ((size_t)(b * XY + h0 + r_out)) * XY * CC;
#pragma unroll
    for (int r = 0; r < 4; ++r) {
      int wp = (mt & 3) * 16 + q * 4 + r;
      float iv = inrow[r_out * 64 + wp];
#pragma unroll
      for (int nt = 0; nt < 4; ++nt) {
        int co = (wv << 6) + nt * 16 + m;
        float val = fmaxf(acc[mt][nt][r] + t2[nt], 0.f);
        ob[(size_t)wp * CC + co] = fmaxf(iv + val, 0.f);
      }
    }
  }
}

extern "C" void kernel_launch(void* const* d_in, const int* in_sizes, int n_in,
                              void* d_out, int out_size, void* d_ws, size_t ws_size,
                              hipStream_t stream) {
  const float* in_   = (const float*)d_in[0];   // (16,64,64)
  const float* w1    = (const float*)d_in[3];   // (256,1,3,3)
  const float* w2    = (const float*)d_in[4];   // (256,256,3,3)
  const float* bn1_g = (const float*)d_in[5];
  const float* bn1_b = (const float*)d_in[6];
  const float* bn1_m = (const float*)d_in[7];
  const float* bn1_v = (const float*)d_in[8];
  const float* bn2_g = (const float*)d_in[9];
  const float* bn2_b = (const float*)d_in[10];
  const float* bn2_m = (const float*)d_in[11];
  const float* bn2_v = (const float*)d_in[12];
  float* out = (float*)d_out;

  // workspace: act bf16 (B,66,66,256) = 35.7 MB, then Wb bf16 (9*8*1024*8) = 1.18 MB
  bf16* act = (bf16*)d_ws;
  bf16* Wb  = act + (size_t)BB * PD * PD * CC;

  k_conv1<<<BB * PD, 256, 0, stream>>>(in_, w1, bn1_g, bn1_b, bn1_m, bn1_v, act);
  k_wb<<<(9 * CC * CC) / 256, 256, 0, stream>>>(w2, bn2_g, bn2_v, Wb);
  k_conv2<<<512, 256, 0, stream>>>(act, Wb, in_, bn2_g, bn2_b, bn2_m, bn2_v, out);
}